// Round 1
// baseline (17201.068 us; speedup 1.0000x reference)
//
#include <hip/hip_runtime.h>
#include <cstdint>
#include <cmath>

// Problem constants
#define V_SZ 5000
#define H_SZ 512
#define N_SZ 8
#define T_LEN 2048
#define NTV (81920000LL)   // N*T*V

typedef __bf16 bf16;
typedef __bf16 bf16x8 __attribute__((ext_vector_type(8)));
typedef float  f32x4  __attribute__((ext_vector_type(4)));

// ---------------------------------------------------------------------------
// Kernel 1: convert Wo (fp32 [5000][512]) -> bf16 padded [5120][512]
// ---------------------------------------------------------------------------
__global__ __launch_bounds__(256) void prep_wo(const float* __restrict__ Wo,
                                               bf16* __restrict__ Wo16) {
    int idx = (blockIdx.x * 256 + threadIdx.x) * 4;   // over 5120*512
    if (idx >= 5120 * 512) return;
    float4 v = make_float4(0.f, 0.f, 0.f, 0.f);
    if (idx < V_SZ * H_SZ) v = *(const float4*)(Wo + idx);
    Wo16[idx + 0] = (bf16)v.x;
    Wo16[idx + 1] = (bf16)v.y;
    Wo16[idx + 2] = (bf16)v.z;
    Wo16[idx + 3] = (bf16)v.w;
}

// ---------------------------------------------------------------------------
// Kernel 2: the sequential recurrence. 64 blocks x 256 threads, persistent.
// Block b owns output columns j in [b*8, b*8+8). Wh slice lives in registers.
// Thread mapping: kc = tid&7 (k-chunk of 64), n = (tid>>3)&7, jg = tid>>6
// (jg covers 2 local j). Cross-block h exchange via global double buffer +
// per-block monotonic flags (device-scope atomics; per-XCD L2 not coherent).
// ---------------------------------------------------------------------------
__global__ __launch_bounds__(256, 1) void rnn_rec(
        const int*   __restrict__ x,
        const float* __restrict__ E,
        const float* __restrict__ Wh,
        const float* __restrict__ bh,
        float*       __restrict__ hb0,
        float*       __restrict__ hb1,
        bf16*        __restrict__ Hall,
        int*         __restrict__ flags,
        float*       __restrict__ out) {
    const int tid = threadIdx.x;
    const int blk = blockIdx.x;          // 0..63
    const int kc  = tid & 7;             // 8 chunks of 64 k
    const int n   = (tid >> 3) & 7;
    const int jg  = tid >> 6;            // 0..3
    const int jb0 = blk * 8;
    const int jl0 = jg * 2, jl1 = jg * 2 + 1;

    __shared__ float part[8][8][8];      // [n][jl][kc]
    __shared__ int   tokL[8];
    __shared__ float bhL[8];

    // Preload Wh slice into registers: 2 rows x 64 k = 32 float4.
    float4 w0[16], w1[16];
    {
        const float4* p0 = (const float4*)(Wh + (size_t)(jb0 + jl0) * H_SZ + kc * 64);
        const float4* p1 = (const float4*)(Wh + (size_t)(jb0 + jl1) * H_SZ + kc * 64);
#pragma unroll
        for (int q = 0; q < 16; ++q) { w0[q] = p0[q]; w1[q] = p1[q]; }
    }
    if (tid < 8) bhL[tid] = bh[jb0 + tid];

    for (int t = 0; t < T_LEN; ++t) {
        // Wait until every block has published h_t (flags[b] >= t).
        if (tid < 64) {
            while (__hip_atomic_load(&flags[tid], __ATOMIC_RELAXED,
                                     __HIP_MEMORY_SCOPE_AGENT) < t) {
                __builtin_amdgcn_s_sleep(1);
            }
        }
        __syncthreads();
        __builtin_amdgcn_fence(__ATOMIC_ACQUIRE, "agent");  // invalidate L1/L2

        if (tid < 8) tokL[tid] = x[tid * T_LEN + t];

        const float* hcur  = (t & 1) ? hb1 : hb0;
        float*       hnext = (t & 1) ? hb0 : hb1;

        const float4* hp = (const float4*)(hcur + n * H_SZ + kc * 64);
        float acc0 = 0.f, acc1 = 0.f;
#pragma unroll
        for (int q = 0; q < 16; ++q) {
            float4 h4 = hp[q];
            acc0 += h4.x * w0[q].x + h4.y * w0[q].y + h4.z * w0[q].z + h4.w * w0[q].w;
            acc1 += h4.x * w1[q].x + h4.y * w1[q].y + h4.z * w1[q].z + h4.w * w1[q].w;
        }
        part[n][jl0][kc] = acc0;
        part[n][jl1][kc] = acc1;
        __syncthreads();

        if (tid < 64) {
            const int n2 = tid >> 3, j2 = tid & 7;
            const float* pr = part[n2][j2];
            float s = pr[0] + pr[1] + pr[2] + pr[3] + pr[4] + pr[5] + pr[6] + pr[7];
            const int tok = tokL[n2];
            const float xh = E[(size_t)tok * H_SZ + jb0 + j2];
            const float hn = tanhf(s + bhL[j2] + xh);
            // publish h_{t+1}: atomic relaxed agent store -> bypass L2, lands at LLC
            __hip_atomic_store(&hnext[n2 * H_SZ + jb0 + j2], hn,
                               __ATOMIC_RELAXED, __HIP_MEMORY_SCOPE_AGENT);
            // bf16 copy for the output GEMM (read by a later kernel - no fence needed)
            Hall[((size_t)n2 * T_LEN + t) * H_SZ + jb0 + j2] = (bf16)hn;
            if (t == T_LEN - 1)
                out[NTV + n2 * H_SZ + jb0 + j2] = hn;
        }
        __syncthreads();
        if (tid == 0)
            __hip_atomic_store(&flags[blk], t + 1, __ATOMIC_RELEASE,
                               __HIP_MEMORY_SCOPE_AGENT);
    }
}

// ---------------------------------------------------------------------------
// Kernel 3: Z = Hall(16384x512 bf16) * Wo16^T(5120x512 bf16) + bo, fp32 out.
// 128x128 tile, BK=64, 256 threads (2x2 waves of 64x64), mfma 16x16x32 bf16.
// LDS rows padded to 72 bf16 (144 B) -> conflict-free ds_read_b128.
// ---------------------------------------------------------------------------
#define LDK 72
__global__ __launch_bounds__(256) void gemm_bt(
        const bf16* __restrict__ A,    // [16384][512]
        const bf16* __restrict__ B,    // [5120][512]
        const float* __restrict__ bo,  // [5000]
        float* __restrict__ C) {       // [16384][5000]
    __shared__ bf16 As[128 * LDK];
    __shared__ bf16 Bs[128 * LDK];

    const int tid  = threadIdx.x;
    const int lane = tid & 63;
    const int wid  = tid >> 6;
    const int wm   = wid & 1, wn = wid >> 1;
    const int bm   = blockIdx.y, bn = blockIdx.x;
    const int rowA0 = bm * 128, rowB0 = bn * 128;

    const int quad = lane >> 4;
    const int l15  = lane & 15;

    f32x4 acc[4][4] = {};

    for (int kt = 0; kt < H_SZ / 64; ++kt) {
        __syncthreads();
        // stage: 1024 16B-chunks each; chunk p: row=p>>3, c8=p&7
#pragma unroll
        for (int i = 0; i < 4; ++i) {
            int p = i * 256 + tid;
            int r = p >> 3, c8 = p & 7;
            bf16x8 va = *(const bf16x8*)(A + (size_t)(rowA0 + r) * H_SZ + kt * 64 + c8 * 8);
            *(bf16x8*)(As + r * LDK + c8 * 8) = va;
            bf16x8 vb = *(const bf16x8*)(B + (size_t)(rowB0 + r) * H_SZ + kt * 64 + c8 * 8);
            *(bf16x8*)(Bs + r * LDK + c8 * 8) = vb;
        }
        __syncthreads();

#pragma unroll
        for (int ks = 0; ks < 2; ++ks) {
            bf16x8 af[4], bf[4];
            const int koff = ks * 32 + quad * 8;
#pragma unroll
            for (int mi = 0; mi < 4; ++mi) {
                int row = wm * 64 + mi * 16 + l15;
                af[mi] = *(const bf16x8*)(As + row * LDK + koff);
            }
#pragma unroll
            for (int ni = 0; ni < 4; ++ni) {
                int row = wn * 64 + ni * 16 + l15;
                bf[ni] = *(const bf16x8*)(Bs + row * LDK + koff);
            }
#pragma unroll
            for (int mi = 0; mi < 4; ++mi)
#pragma unroll
                for (int ni = 0; ni < 4; ++ni)
                    acc[mi][ni] = __builtin_amdgcn_mfma_f32_16x16x32_bf16(
                        af[mi], bf[ni], acc[mi][ni], 0, 0, 0);
        }
    }

    // Epilogue: C[m][v] = acc + bo[v]   (C/D layout: col=lane&15, row=quad*4+r)
#pragma unroll
    for (int mi = 0; mi < 4; ++mi) {
#pragma unroll
        for (int ni = 0; ni < 4; ++ni) {
            int vcol = rowB0 + wn * 64 + ni * 16 + l15;
            if (vcol >= V_SZ) continue;
            float bias = bo[vcol];
#pragma unroll
            for (int r = 0; r < 4; ++r) {
                int m = rowA0 + wm * 64 + mi * 16 + quad * 4 + r;
                C[(size_t)m * V_SZ + vcol] = acc[mi][ni][r] + bias;
            }
        }
    }
}

// ---------------------------------------------------------------------------
// Kernel 4: in-place row softmax over V=5000. One block per row.
// ---------------------------------------------------------------------------
__global__ __launch_bounds__(256) void softmax_rows(float* __restrict__ z) {
    __shared__ float buf[5008];
    __shared__ float red[8];
    const int tid = threadIdx.x;
    const int lane = tid & 63;
    const int wid = tid >> 6;
    const size_t base = (size_t)blockIdx.x * V_SZ;

    float lm = -3.4e38f;
    for (int i = tid; i < V_SZ; i += 256) {
        float v = z[base + i];
        buf[i] = v;
        lm = fmaxf(lm, v);
    }
#pragma unroll
    for (int o = 32; o; o >>= 1) lm = fmaxf(lm, __shfl_down(lm, o, 64));
    if (lane == 0) red[wid] = lm;
    __syncthreads();
    const float m = fmaxf(fmaxf(red[0], red[1]), fmaxf(red[2], red[3]));

    float ls = 0.f;
    for (int i = tid; i < V_SZ; i += 256) {
        float e = __expf(buf[i] - m);
        buf[i] = e;
        ls += e;
    }
#pragma unroll
    for (int o = 32; o; o >>= 1) ls += __shfl_down(ls, o, 64);
    __syncthreads();
    if (lane == 0) red[4 + wid] = ls;
    __syncthreads();
    const float inv = 1.0f / (red[4] + red[5] + red[6] + red[7]);
    for (int i = tid; i < V_SZ; i += 256) z[base + i] = buf[i] * inv;
}

// ---------------------------------------------------------------------------
// Workspace layout (bytes):
//   [0,256)        flags (64 ints)
//   [1024,33792)   h double buffer (2 x 4096 floats)
//   [65536,...)    Wo16 bf16 [5120*512]   (5,242,880 B)
//   [8388608,...)  Hall bf16 [16384*512]  (16,777,216 B)   total ~24 MiB
// ---------------------------------------------------------------------------
extern "C" void kernel_launch(void* const* d_in, const int* in_sizes, int n_in,
                              void* d_out, int out_size, void* d_ws, size_t ws_size,
                              hipStream_t stream) {
    const int*   x  = (const int*)d_in[0];
    const float* E  = (const float*)d_in[1];
    const float* Wh = (const float*)d_in[2];
    const float* bh = (const float*)d_in[3];
    const float* Wo = (const float*)d_in[4];
    const float* bo = (const float*)d_in[5];
    float* out = (float*)d_out;

    char* ws = (char*)d_ws;
    int*   flags = (int*)ws;
    float* hb0   = (float*)(ws + 1024);
    float* hb1   = (float*)(ws + 1024 + 16384);
    bf16*  Wo16  = (bf16*)(ws + 65536);
    bf16*  Hall  = (bf16*)(ws + 8388608);

    // zero flags + h0 (harness poisons ws with 0xAA before every launch)
    hipMemsetAsync(ws, 0, 33792, stream);

    prep_wo<<<2560, 256, 0, stream>>>(Wo, Wo16);
    rnn_rec<<<64, 256, 0, stream>>>(x, E, Wh, bh, hb0, hb1, Hall, flags, out);
    gemm_bt<<<dim3(40, 128), 256, 0, stream>>>(Hall, Wo16, bo, out);
    softmax_rows<<<16384, 256, 0, stream>>>(out);
}

// Round 2
// 17199.825 us; speedup vs baseline: 1.0001x; 1.0001x over previous
//
#include <hip/hip_runtime.h>
#include <cstdint>
#include <cmath>

// Problem constants
#define V_SZ 5000
#define H_SZ 512
#define N_SZ 8
#define T_LEN 2048
#define NTV (81920000LL)   // N*T*V

typedef __bf16 bf16;
typedef __bf16 bf16x8 __attribute__((ext_vector_type(8)));
typedef float  f32x4  __attribute__((ext_vector_type(4)));
typedef int    i32x4  __attribute__((ext_vector_type(4)));

// ---------------------------------------------------------------------------
// LLC-coherent 16B accesses (bypass L1+L2 via sc0 sc1). A chunk is
// [data0, tag, data1, tag] so even an 8B split cannot tear data from its tag.
// ---------------------------------------------------------------------------
__device__ __forceinline__ void llc_store16(void* p, i32x4 v) {
    asm volatile("global_store_dwordx4 %0, %1, off sc0 sc1"
                 :: "v"(p), "v"(v) : "memory");
}
__device__ __forceinline__ void llc_load2(const void* p0, const void* p1,
                                          i32x4& a, i32x4& b) {
    asm volatile("global_load_dwordx4 %0, %2, off sc0 sc1\n\t"
                 "global_load_dwordx4 %1, %3, off sc0 sc1\n\t"
                 "s_waitcnt vmcnt(0)"
                 : "=&v"(a), "=&v"(b)
                 : "v"(p0), "v"(p1)
                 : "memory");
}

// ---------------------------------------------------------------------------
// Kernel 1: convert Wo (fp32 [5000][512]) -> bf16 padded [5120][512]
// ---------------------------------------------------------------------------
__global__ __launch_bounds__(256) void prep_wo(const float* __restrict__ Wo,
                                               bf16* __restrict__ Wo16) {
    int idx = (blockIdx.x * 256 + threadIdx.x) * 4;   // over 5120*512
    if (idx >= 5120 * 512) return;
    float4 v = make_float4(0.f, 0.f, 0.f, 0.f);
    if (idx < V_SZ * H_SZ) v = *(const float4*)(Wo + idx);
    Wo16[idx + 0] = (bf16)v.x;
    Wo16[idx + 1] = (bf16)v.y;
    Wo16[idx + 2] = (bf16)v.z;
    Wo16[idx + 3] = (bf16)v.w;
}

// ---------------------------------------------------------------------------
// Kernel 2: recurrence. 16 blocks x 1024 threads. Block b owns j in
// [32b, 32b+32). Wh slice in registers (thread (jl,kq): 16 weights).
// Exchange: self-tagged 16B chunks at LLC, one round trip per step.
//   Hx[parity][block][128 chunks]: chunk = [h(2pi), tag, h(2pi+1), tag],
//   tag = h-index (t+1 published at step t). Poison 0xAAAAAAAA never matches.
// ---------------------------------------------------------------------------
__global__ __launch_bounds__(1024, 1) void rnn_rec2(
        const int*   __restrict__ x,
        const float* __restrict__ E,
        const float* __restrict__ Wh,
        const float* __restrict__ bh,
        i32x4*       __restrict__ Hx,
        bf16*        __restrict__ Hall,
        float*       __restrict__ out) {
    __shared__ float hL[8 * 512];          // full current h, 16 KB
    __shared__ float part[8 * 32 * 17];    // padded partials, 17.4 KB
    __shared__ float hnewL[8 * 32];        // this block's new slice

    const int tid = threadIdx.x;
    const int blk = blockIdx.x;            // 0..15
    const int jl  = tid & 31;              // local j
    const int kq  = tid >> 5;              // 0..31 -> k range [16kq,16kq+16)
    const int j0  = blk * 32;
    const int wv  = tid >> 6;              // wave id 0..15

    for (int i = tid; i < 8 * 512; i += 1024) hL[i] = 0.f;

    // Wh slice -> registers (one-time)
    float w[16];
    {
        const float* wp = Wh + (size_t)(j0 + jl) * H_SZ + kq * 16;
#pragma unroll
        for (int i = 0; i < 16; ++i) w[i] = wp[i];
    }

    // reducer-role constants (threads 0..255 handle output (rn, rj))
    const int rn = tid >> 5, rj = tid & 31;         // valid for tid<256
    float bhv = (tid < 256) ? bh[j0 + rj] : 0.f;

    // reader chunk assignment: 15 slices x 128 chunks = 1920, 16B each.
    // c -> s_idx=c>>7, cc=c&127, n=cc>>4, pi=cc&15
    int  off0 = 0, off1 = 0, dst0 = 0, dst1 = 0;
    bool has1;
    {
        int c0 = tid;
        int s0 = c0 >> 7, cc0 = c0 & 127;
        int sb0 = s0 + (s0 >= blk);
        off0 = (sb0 * 128 + cc0) * 16;
        dst0 = (cc0 >> 4) * 512 + sb0 * 32 + 2 * (cc0 & 15);
        int c1 = tid + 1024;
        has1 = (c1 < 1920);
        int c1c = has1 ? c1 : c0;
        int s1 = c1c >> 7, cc1 = c1c & 127;
        int sb1 = s1 + (s1 >= blk);
        off1 = (sb1 * 128 + cc1) * 16;
        dst1 = (cc1 >> 4) * 512 + sb1 * 32 + 2 * (cc1 & 15);
    }

    int budget = 1 << 22;   // safety: terminate even if coherence breaks
    __syncthreads();

    for (int t = 0; t < T_LEN; ++t) {
        // P0: prefetch token + embedding for this step (used in P4)
        float ev = 0.f;
        if (tid < 256) {
            int tok = x[rn * T_LEN + t];
            ev = E[(size_t)tok * H_SZ + j0 + rj];
        }

        // P1: gather the other 15 slices of h_t (self-tagged chunks)
        if (t > 0) {
            const char* base = (const char*)Hx + (size_t)(t & 1) * 32768;
            const int wtag = t;
            const void* p0 = base + off0;
            const void* p1 = base + off1;
            bool need0 = true, need1 = has1;
            while (need0 | need1) {
                i32x4 a, b;
                llc_load2(p0, p1, a, b);
                if (need0 & (a.y == wtag) & (a.w == wtag)) {
                    hL[dst0]     = __int_as_float(a.x);
                    hL[dst0 + 1] = __int_as_float(a.z);
                    need0 = false;
                }
                if (need1 & (b.y == wtag) & (b.w == wtag)) {
                    hL[dst1]     = __int_as_float(b.x);
                    hL[dst1 + 1] = __int_as_float(b.z);
                    need1 = false;
                }
                if (--budget < 0) break;
            }
        }
        __syncthreads();

        // P3: MACs. thread (jl,kq): acc[n] = sum_{k in 16kq..} h[n][k]*w[k]
        float acc[8];
        {
            const float* hbase = hL + kq * 16;
#pragma unroll
            for (int n = 0; n < 8; ++n) {
                const float4* hp = (const float4*)(hbase + n * 512);
                float4 h0 = hp[0], h1 = hp[1], h2 = hp[2], h3 = hp[3];
                float s;
                s  = h0.x * w[0]  + h0.y * w[1]  + h0.z * w[2]  + h0.w * w[3];
                s += h1.x * w[4]  + h1.y * w[5]  + h1.z * w[6]  + h1.w * w[7];
                s += h2.x * w[8]  + h2.y * w[9]  + h2.z * w[10] + h2.w * w[11];
                s += h3.x * w[12] + h3.y * w[13] + h3.z * w[14] + h3.w * w[15];
                acc[n] = s;
            }
        }
        // pair-reduce across the two kq's of this wave, write padded partials
#pragma unroll
        for (int n = 0; n < 8; ++n) {
            float s = acc[n] + __shfl_xor(acc[n], 32, 64);
            if ((tid & 63) < 32) part[(n * 32 + jl) * 17 + wv] = s;
        }
        __syncthreads();

        // P4: final reduce + tanh + bookkeeping (threads 0..255)
        if (tid < 256) {
            const float* pp = part + tid * 17;
            float s = 0.f;
#pragma unroll
            for (int i = 0; i < 16; ++i) s += pp[i];
            float h = tanhf(s + bhv + ev);
            hnewL[tid] = h;
            hL[rn * 512 + j0 + rj] = h;                       // own slice local
            Hall[((size_t)rn * T_LEN + t) * H_SZ + j0 + rj] = (bf16)h;
            if (t == T_LEN - 1) out[NTV + rn * H_SZ + j0 + rj] = h;
        }
        __syncthreads();

        // P6: publish own slice as tagged chunks (threads 0..127)
        if (tid < 128 && t < T_LEN - 1) {
            int n = tid >> 4, pi = tid & 15;
            i32x4 ch;
            ch.x = __float_as_int(hnewL[n * 32 + 2 * pi]);
            ch.y = t + 1;
            ch.z = __float_as_int(hnewL[n * 32 + 2 * pi + 1]);
            ch.w = t + 1;
            char* dstp = (char*)Hx + (size_t)((t + 1) & 1) * 32768
                       + (blk * 128 + tid) * 16;
            llc_store16(dstp, ch);
        }
    }
}

// ---------------------------------------------------------------------------
// Kernel 3: Z = Hall(16384x512 bf16) * Wo16^T(5120x512 bf16) + bo, fp32 out.
// ---------------------------------------------------------------------------
#define LDK 72
__global__ __launch_bounds__(256) void gemm_bt(
        const bf16* __restrict__ A,    // [16384][512]
        const bf16* __restrict__ B,    // [5120][512]
        const float* __restrict__ bo,  // [5000]
        float* __restrict__ C) {       // [16384][5000]
    __shared__ bf16 As[128 * LDK];
    __shared__ bf16 Bs[128 * LDK];

    const int tid  = threadIdx.x;
    const int lane = tid & 63;
    const int wid  = tid >> 6;
    const int wm   = wid & 1, wn = wid >> 1;
    const int bm   = blockIdx.y, bn = blockIdx.x;
    const int rowA0 = bm * 128, rowB0 = bn * 128;

    const int quad = lane >> 4;
    const int l15  = lane & 15;

    f32x4 acc[4][4] = {};

    for (int kt = 0; kt < H_SZ / 64; ++kt) {
        __syncthreads();
#pragma unroll
        for (int i = 0; i < 4; ++i) {
            int p = i * 256 + tid;
            int r = p >> 3, c8 = p & 7;
            bf16x8 va = *(const bf16x8*)(A + (size_t)(rowA0 + r) * H_SZ + kt * 64 + c8 * 8);
            *(bf16x8*)(As + r * LDK + c8 * 8) = va;
            bf16x8 vb = *(const bf16x8*)(B + (size_t)(rowB0 + r) * H_SZ + kt * 64 + c8 * 8);
            *(bf16x8*)(Bs + r * LDK + c8 * 8) = vb;
        }
        __syncthreads();

#pragma unroll
        for (int ks = 0; ks < 2; ++ks) {
            bf16x8 af[4], bfr[4];
            const int koff = ks * 32 + quad * 8;
#pragma unroll
            for (int mi = 0; mi < 4; ++mi) {
                int row = wm * 64 + mi * 16 + l15;
                af[mi] = *(const bf16x8*)(As + row * LDK + koff);
            }
#pragma unroll
            for (int ni = 0; ni < 4; ++ni) {
                int row = wn * 64 + ni * 16 + l15;
                bfr[ni] = *(const bf16x8*)(Bs + row * LDK + koff);
            }
#pragma unroll
            for (int mi = 0; mi < 4; ++mi)
#pragma unroll
                for (int ni = 0; ni < 4; ++ni)
                    acc[mi][ni] = __builtin_amdgcn_mfma_f32_16x16x32_bf16(
                        af[mi], bfr[ni], acc[mi][ni], 0, 0, 0);
        }
    }

#pragma unroll
    for (int mi = 0; mi < 4; ++mi) {
#pragma unroll
        for (int ni = 0; ni < 4; ++ni) {
            int vcol = rowB0 + wn * 64 + ni * 16 + l15;
            if (vcol >= V_SZ) continue;
            float bias = bo[vcol];
#pragma unroll
            for (int r = 0; r < 4; ++r) {
                int m = rowA0 + wm * 64 + mi * 16 + quad * 4 + r;
                C[(size_t)m * V_SZ + vcol] = acc[mi][ni][r] + bias;
            }
        }
    }
}

// ---------------------------------------------------------------------------
// Kernel 4: in-place row softmax over V=5000. One block per row.
// ---------------------------------------------------------------------------
__global__ __launch_bounds__(256) void softmax_rows(float* __restrict__ z) {
    __shared__ float buf[5008];
    __shared__ float red[8];
    const int tid = threadIdx.x;
    const int lane = tid & 63;
    const int wid = tid >> 6;
    const size_t base = (size_t)blockIdx.x * V_SZ;

    float lm = -3.4e38f;
    for (int i = tid; i < V_SZ; i += 256) {
        float v = z[base + i];
        buf[i] = v;
        lm = fmaxf(lm, v);
    }
#pragma unroll
    for (int o = 32; o; o >>= 1) lm = fmaxf(lm, __shfl_down(lm, o, 64));
    if (lane == 0) red[wid] = lm;
    __syncthreads();
    const float m = fmaxf(fmaxf(red[0], red[1]), fmaxf(red[2], red[3]));

    float ls = 0.f;
    for (int i = tid; i < V_SZ; i += 256) {
        float e = __expf(buf[i] - m);
        buf[i] = e;
        ls += e;
    }
#pragma unroll
    for (int o = 32; o; o >>= 1) ls += __shfl_down(ls, o, 64);
    __syncthreads();
    if (lane == 0) red[4 + wid] = ls;
    __syncthreads();
    const float inv = 1.0f / (red[4] + red[5] + red[6] + red[7]);
    for (int i = tid; i < V_SZ; i += 256) z[base + i] = buf[i] * inv;
}

// ---------------------------------------------------------------------------
// Workspace layout (bytes):
//   [0, 65536)      Hx tagged exchange buffers (2 x 16 x 128 x 16 B)
//   [65536, ...)    Wo16 bf16 [5120*512]   (5,242,880 B)
//   [8388608, ...)  Hall bf16 [16384*512]  (16,777,216 B)
// No memset needed: Hx tags are exact-match (poison 0xAAAAAAAA never valid),
// h0=0 handled by skipping the exchange at t=0.
// ---------------------------------------------------------------------------
extern "C" void kernel_launch(void* const* d_in, const int* in_sizes, int n_in,
                              void* d_out, int out_size, void* d_ws, size_t ws_size,
                              hipStream_t stream) {
    const int*   x  = (const int*)d_in[0];
    const float* E  = (const float*)d_in[1];
    const float* Wh = (const float*)d_in[2];
    const float* bh = (const float*)d_in[3];
    const float* Wo = (const float*)d_in[4];
    const float* bo = (const float*)d_in[5];
    float* out = (float*)d_out;

    char* ws = (char*)d_ws;
    i32x4* Hx   = (i32x4*)ws;
    bf16*  Wo16 = (bf16*)(ws + 65536);
    bf16*  Hall = (bf16*)(ws + 8388608);

    prep_wo<<<2560, 256, 0, stream>>>(Wo, Wo16);
    rnn_rec2<<<16, 1024, 0, stream>>>(x, E, Wh, bh, Hx, Hall, out);
    gemm_bt<<<dim3(40, 128), 256, 0, stream>>>(Hall, Wo16, bo, out);
    softmax_rows<<<16384, 256, 0, stream>>>(out);
}

// Round 3
// 6323.844 us; speedup vs baseline: 2.7200x; 2.7198x over previous
//
#include <hip/hip_runtime.h>
#include <cstdint>
#include <cmath>

// Problem constants
#define V_SZ 5000
#define H_SZ 512
#define N_SZ 8
#define T_LEN 2048
#define NTV (81920000LL)   // N*T*V

typedef __bf16 bf16;
typedef __bf16 bf16x2 __attribute__((ext_vector_type(2)));
typedef __bf16 bf16x8 __attribute__((ext_vector_type(8)));
typedef float  f32x4  __attribute__((ext_vector_type(4)));
typedef int    i32x4  __attribute__((ext_vector_type(4)));

// ---------------------------------------------------------------------------
// LLC-coherent 16B accesses (bypass L1+L2 via sc0 sc1). A chunk is
// [data0, tag, data1, tag] so an 8B split cannot tear data from its tag.
// ---------------------------------------------------------------------------
__device__ __forceinline__ void llc_store16(void* p, i32x4 v) {
    asm volatile("global_store_dwordx4 %0, %1, off sc0 sc1"
                 :: "v"(p), "v"(v) : "memory");
}
__device__ __forceinline__ void llc_load2(const void* p0, const void* p1,
                                          i32x4& a, i32x4& b) {
    asm volatile("global_load_dwordx4 %0, %2, off sc0 sc1\n\t"
                 "global_load_dwordx4 %1, %3, off sc0 sc1\n\t"
                 "s_waitcnt vmcnt(0)"
                 : "=&v"(a), "=&v"(b)
                 : "v"(p0), "v"(p1)
                 : "memory");
}

// ---------------------------------------------------------------------------
// Kernel 1: convert Wo (fp32 [5000][512]) -> bf16 padded [5120][512]
// ---------------------------------------------------------------------------
__global__ __launch_bounds__(256) void prep_wo(const float* __restrict__ Wo,
                                               bf16* __restrict__ Wo16) {
    int idx = (blockIdx.x * 256 + threadIdx.x) * 4;
    if (idx >= 5120 * 512) return;
    float4 v = make_float4(0.f, 0.f, 0.f, 0.f);
    if (idx < V_SZ * H_SZ) v = *(const float4*)(Wo + idx);
    Wo16[idx + 0] = (bf16)v.x;
    Wo16[idx + 1] = (bf16)v.y;
    Wo16[idx + 2] = (bf16)v.z;
    Wo16[idx + 3] = (bf16)v.w;
}

// ---------------------------------------------------------------------------
// Kernel 2: recurrence, 4 blocks x 1024 threads. Block b owns j in
// [128b, 128b+128). MFMA formulation per step:
//   A (M=16): rows 0-7 = h_hi (bf16 of h, 8 batches), rows 8-15 = h_lo
//   (bf16 of h - h_hi). Waves 0-7: B = W_hi bf16 frags (j-tile = wave id);
//   waves 8-15: B = W_lo frags. s = sum of 4 D quadrants ~= fp32-exact.
//   W frags resident in VGPRs (64/thread). A in LDS, stride 520 bf16.
// Exchange: self-tagged 16B LLC chunks, 512 per block per step.
// ---------------------------------------------------------------------------
__global__ __launch_bounds__(1024, 1) void rnn_rec3(
        const int*   __restrict__ x,
        const float* __restrict__ E,
        const float* __restrict__ Wh,
        const float* __restrict__ bh,
        char*        __restrict__ Hx,
        bf16*        __restrict__ Hall,
        float*       __restrict__ out) {
    __shared__ bf16  Abuf[2 * 16 * 520];    // 33.3 KB, double-buffered A
    __shared__ float Ds[16 * 272];          // 17.4 KB, D per wave, stride 17
    __shared__ float hnewL[1024];
    __shared__ int   tokL[8];

    const int tid  = threadIdx.x;
    const int blk  = blockIdx.x;            // 0..3
    const int lane = tid & 63;
    const int wv   = tid >> 6;              // 0..15
    const int l15  = lane & 15;
    const int quad = lane >> 4;
    const int j0   = blk * 128;

    // zero both A buffers (h0 = 0)
    for (int i = tid; i < 2 * 16 * 520; i += 1024) Abuf[i] = (bf16)0.f;

    // W fragments -> registers. Wave w<8: W_hi of j-tile w; w>=8: W_lo of w-8.
    bf16x8 wf[16];
    {
        const float* wrow = Wh + (size_t)(j0 + (wv & 7) * 16 + l15) * H_SZ;
        const bool lo_pass = (wv >= 8);
#pragma unroll
        for (int kt = 0; kt < 16; ++kt) {
            const float* p = wrow + kt * 32 + quad * 8;
            bf16x8 f;
#pragma unroll
            for (int i = 0; i < 8; ++i) {
                float v = p[i];
                bf16 hi = (bf16)v;
                f[i] = lo_pass ? (bf16)(v - (float)hi) : hi;
            }
            wf[kt] = f;
        }
    }

    const int rn = tid >> 7, rj = tid & 127;   // reducer output (batch, local j)
    const float bhv = bh[j0 + rj];
    const int jt = rj >> 4, jl = rj & 15;

    // reader chunk precompute: 3 remote blocks x 512 chunks = 1536
    int off0, off1, dst0, dst1;
    bool has1 = (tid < 512);
    {
        int c0 = tid;
        int rbp0 = c0 >> 9, cc0 = c0 & 511;
        int rb0 = rbp0 + (rbp0 >= blk);
        off0 = (rb0 * 512 + cc0) * 16;
        dst0 = (cc0 >> 6) * 520 + rb0 * 128 + 2 * (cc0 & 63);
        int c1 = has1 ? (tid + 1024) : c0;
        int rbp1 = c1 >> 9, cc1 = c1 & 511;
        int rb1 = rbp1 + (rbp1 >= blk);
        off1 = (rb1 * 512 + cc1) * 16;
        dst1 = (cc1 >> 6) * 520 + rb1 * 128 + 2 * (cc1 & 63);
    }

    int budget = 1 << 22;
    __syncthreads();

    for (int t = 0; t < T_LEN; ++t) {
        if (tid < 8) tokL[tid] = x[tid * T_LEN + t];

        // P1: gather remote slices of h_t into A[t&1]
        if (t > 0) {
            const char* base = Hx + (size_t)(t & 1) * 32768;
            bf16* An = Abuf + (t & 1) * (16 * 520);
            const int wtag = t;
            const void* p0 = base + off0;
            const void* p1 = base + off1;
            bool need0 = true, need1 = has1;
            while (need0 | need1) {
                i32x4 a, b;
                llc_load2(p0, p1, a, b);
                if (need0 & (a.y == wtag) & (a.w == wtag)) {
                    float h0 = __int_as_float(a.x), h1 = __int_as_float(a.z);
                    bf16 hi0 = (bf16)h0, hi1 = (bf16)h1;
                    *(bf16x2*)(An + dst0) = (bf16x2){hi0, hi1};
                    *(bf16x2*)(An + 8 * 520 + dst0) =
                        (bf16x2){(bf16)(h0 - (float)hi0), (bf16)(h1 - (float)hi1)};
                    need0 = false;
                }
                if (need1 & (b.y == wtag) & (b.w == wtag)) {
                    float h0 = __int_as_float(b.x), h1 = __int_as_float(b.z);
                    bf16 hi0 = (bf16)h0, hi1 = (bf16)h1;
                    *(bf16x2*)(An + dst1) = (bf16x2){hi0, hi1};
                    *(bf16x2*)(An + 8 * 520 + dst1) =
                        (bf16x2){(bf16)(h0 - (float)hi0), (bf16)(h1 - (float)hi1)};
                    need1 = false;
                }
                if (--budget < 0) break;
            }
        }
        __syncthreads();

        // embedding prefetch (overlaps MFMA below)
        const float ev = E[(size_t)tokL[rn] * H_SZ + j0 + rj];

        // P3: MFMA  D[m][j] = A[m][k] * W[j][k]
        {
            const bf16* Ab = Abuf + (t & 1) * (16 * 520);
            f32x4 acc = {};
#pragma unroll
            for (int kt = 0; kt < 16; ++kt) {
                bf16x8 af = *(const bf16x8*)(Ab + l15 * 520 + kt * 32 + quad * 8);
                acc = __builtin_amdgcn_mfma_f32_16x16x32_bf16(af, wf[kt], acc, 0, 0, 0);
            }
#pragma unroll
            for (int r = 0; r < 4; ++r)
                Ds[wv * 272 + (quad * 4 + r) * 17 + l15] = acc[r];
        }
        __syncthreads();

        // P4: reduce 4 quadrants + tanh; stage h_{t+1}
        {
            float s = Ds[jt * 272 + rn * 17 + jl]
                    + Ds[jt * 272 + (rn + 8) * 17 + jl]
                    + Ds[(jt + 8) * 272 + rn * 17 + jl]
                    + Ds[(jt + 8) * 272 + (rn + 8) * 17 + jl];
            float h = tanhf(s + bhv + ev);
            hnewL[rn * 128 + rj] = h;
            Hall[((size_t)rn * T_LEN + t) * H_SZ + j0 + rj] = (bf16)h;
            bf16 hi = (bf16)h;
            bf16* An = Abuf + ((t + 1) & 1) * (16 * 520);
            An[rn * 520 + j0 + rj] = hi;
            An[(rn + 8) * 520 + j0 + rj] = (bf16)(h - (float)hi);
            if (t == T_LEN - 1) out[NTV + rn * H_SZ + j0 + rj] = h;
        }
        __syncthreads();

        // P6: publish own slice (512 tagged chunks)
        if (has1 && t < T_LEN - 1) {
            int n = tid >> 6, jp = tid & 63;
            i32x4 ch;
            ch.x = __float_as_int(hnewL[n * 128 + 2 * jp]);
            ch.y = t + 1;
            ch.z = __float_as_int(hnewL[n * 128 + 2 * jp + 1]);
            ch.w = t + 1;
            char* dstp = Hx + (size_t)((t + 1) & 1) * 32768 + (blk * 512 + tid) * 16;
            llc_store16(dstp, ch);
        }
    }
}

// ---------------------------------------------------------------------------
// Kernel 3: Z = Hall(16384x512 bf16) * Wo16^T(5120x512 bf16) + bo, fp32 out.
// ---------------------------------------------------------------------------
#define LDK 72
__global__ __launch_bounds__(256) void gemm_bt(
        const bf16* __restrict__ A,
        const bf16* __restrict__ B,
        const float* __restrict__ bo,
        float* __restrict__ C) {
    __shared__ bf16 As[128 * LDK];
    __shared__ bf16 Bs[128 * LDK];

    const int tid  = threadIdx.x;
    const int lane = tid & 63;
    const int wid  = tid >> 6;
    const int wm   = wid & 1, wn = wid >> 1;
    const int bm   = blockIdx.y, bn = blockIdx.x;
    const int rowA0 = bm * 128, rowB0 = bn * 128;

    const int quad = lane >> 4;
    const int l15  = lane & 15;

    f32x4 acc[4][4] = {};

    for (int kt = 0; kt < H_SZ / 64; ++kt) {
        __syncthreads();
#pragma unroll
        for (int i = 0; i < 4; ++i) {
            int p = i * 256 + tid;
            int r = p >> 3, c8 = p & 7;
            bf16x8 va = *(const bf16x8*)(A + (size_t)(rowA0 + r) * H_SZ + kt * 64 + c8 * 8);
            *(bf16x8*)(As + r * LDK + c8 * 8) = va;
            bf16x8 vb = *(const bf16x8*)(B + (size_t)(rowB0 + r) * H_SZ + kt * 64 + c8 * 8);
            *(bf16x8*)(Bs + r * LDK + c8 * 8) = vb;
        }
        __syncthreads();

#pragma unroll
        for (int ks = 0; ks < 2; ++ks) {
            bf16x8 af[4], bfr[4];
            const int koff = ks * 32 + quad * 8;
#pragma unroll
            for (int mi = 0; mi < 4; ++mi) {
                int row = wm * 64 + mi * 16 + l15;
                af[mi] = *(const bf16x8*)(As + row * LDK + koff);
            }
#pragma unroll
            for (int ni = 0; ni < 4; ++ni) {
                int row = wn * 64 + ni * 16 + l15;
                bfr[ni] = *(const bf16x8*)(Bs + row * LDK + koff);
            }
#pragma unroll
            for (int mi = 0; mi < 4; ++mi)
#pragma unroll
                for (int ni = 0; ni < 4; ++ni)
                    acc[mi][ni] = __builtin_amdgcn_mfma_f32_16x16x32_bf16(
                        af[mi], bfr[ni], acc[mi][ni], 0, 0, 0);
        }
    }

#pragma unroll
    for (int mi = 0; mi < 4; ++mi) {
#pragma unroll
        for (int ni = 0; ni < 4; ++ni) {
            int vcol = rowB0 + wn * 64 + ni * 16 + l15;
            if (vcol >= V_SZ) continue;
            float bias = bo[vcol];
#pragma unroll
            for (int r = 0; r < 4; ++r) {
                int m = rowA0 + wm * 64 + mi * 16 + quad * 4 + r;
                C[(size_t)m * V_SZ + vcol] = acc[mi][ni][r] + bias;
            }
        }
    }
}

// ---------------------------------------------------------------------------
// Kernel 4: in-place row softmax over V=5000. One block per row.
// ---------------------------------------------------------------------------
__global__ __launch_bounds__(256) void softmax_rows(float* __restrict__ z) {
    __shared__ float buf[5008];
    __shared__ float red[8];
    const int tid = threadIdx.x;
    const int lane = tid & 63;
    const int wid = tid >> 6;
    const size_t base = (size_t)blockIdx.x * V_SZ;

    float lm = -3.4e38f;
    for (int i = tid; i < V_SZ; i += 256) {
        float v = z[base + i];
        buf[i] = v;
        lm = fmaxf(lm, v);
    }
#pragma unroll
    for (int o = 32; o; o >>= 1) lm = fmaxf(lm, __shfl_down(lm, o, 64));
    if (lane == 0) red[wid] = lm;
    __syncthreads();
    const float m = fmaxf(fmaxf(red[0], red[1]), fmaxf(red[2], red[3]));

    float ls = 0.f;
    for (int i = tid; i < V_SZ; i += 256) {
        float e = __expf(buf[i] - m);
        buf[i] = e;
        ls += e;
    }
#pragma unroll
    for (int o = 32; o; o >>= 1) ls += __shfl_down(ls, o, 64);
    __syncthreads();
    if (lane == 0) red[4 + wid] = ls;
    __syncthreads();
    const float inv = 1.0f / (red[4] + red[5] + red[6] + red[7]);
    for (int i = tid; i < V_SZ; i += 256) z[base + i] = buf[i] * inv;
}

// ---------------------------------------------------------------------------
// Workspace layout (bytes):
//   [0, 65536)      Hx tagged exchange (2 parity x 4 blk x 512 chunks x 16B)
//   [65536, ...)    Wo16 bf16 [5120*512]
//   [8388608, ...)  Hall bf16 [16384*512]
// No memset needed: tags are exact-match; A-LDS zeroed in-kernel.
// ---------------------------------------------------------------------------
extern "C" void kernel_launch(void* const* d_in, const int* in_sizes, int n_in,
                              void* d_out, int out_size, void* d_ws, size_t ws_size,
                              hipStream_t stream) {
    const int*   x  = (const int*)d_in[0];
    const float* E  = (const float*)d_in[1];
    const float* Wh = (const float*)d_in[2];
    const float* bh = (const float*)d_in[3];
    const float* Wo = (const float*)d_in[4];
    const float* bo = (const float*)d_in[5];
    float* out = (float*)d_out;

    char* ws = (char*)d_ws;
    char*  Hx   = ws;
    bf16*  Wo16 = (bf16*)(ws + 65536);
    bf16*  Hall = (bf16*)(ws + 8388608);

    prep_wo<<<2560, 256, 0, stream>>>(Wo, Wo16);
    rnn_rec3<<<4, 1024, 0, stream>>>(x, E, Wh, bh, Hx, Hall, out);
    gemm_bt<<<dim3(40, 128), 256, 0, stream>>>(Hall, Wo16, bo, out);
    softmax_rows<<<16384, 256, 0, stream>>>(out);
}